// Round 9
// baseline (7431.425 us; speedup 1.0000x reference)
//
#include <hip/hip_runtime.h>
#include <stdint.h>

typedef unsigned short u16;
typedef unsigned long long u64;
typedef __attribute__((ext_vector_type(8))) _Float16 f16x8;
typedef __attribute__((ext_vector_type(4))) float f32x4;

#define AGT __HIP_MEMORY_SCOPE_AGENT

// ---------- helpers ----------
__device__ inline f16x8 ldfrag(const u16* p) { return *(const f16x8*)p; }   // cached (weights, pre-written inputs)
__device__ inline u64 ldq_dev(const void* p) {                               // LLC-coherent load
    return __hip_atomic_load((const u64*)p, __ATOMIC_RELAXED, AGT);
}
__device__ inline void stq_dev(void* p, u64 v) {                             // LLC-coherent store
    __hip_atomic_store((u64*)p, v, __ATOMIC_RELAXED, AGT);
}
__device__ inline f16x8 ldfrag_dev(const u16* p) {
    union { u64 q[2]; f16x8 v; } u;
    u.q[0] = ldq_dev(p);
    u.q[1] = ldq_dev(p + 4);
    return u.v;
}
__device__ inline u16 f2h(float x) {
    _Float16 h = (_Float16)x;
    union { _Float16 h; u16 u; } v; v.h = h;
    return v.u;
}
__device__ inline float sigmoidf_(float x) { return 1.0f / (1.0f + expf(-x)); }

// grid barrier without L2 writeback-invalidate
__device__ inline void gbar(unsigned* bars, int ph) {
    __syncthreads();
    if (threadIdx.x == 0) {
        __hip_atomic_fetch_add(&bars[ph], 1u, __ATOMIC_RELAXED, AGT);
        while (__hip_atomic_load(&bars[ph], __ATOMIC_RELAXED, AGT) < 256u)
            __builtin_amdgcn_s_sleep(1);
    }
    __syncthreads();
}

// Layouts (fp16 as u16):
//  A-frag (X: 256 x K): AF[mt][kb][lane][8] = X[mt*16+(lane&15)][kb*32+(lane>>4)*8+j], mt in [0,16)
//  B-frag (W: N x K):   BF[grp][sub][kb][lane][8], row = grp*S2 + (sub%nsub1)*16 + (sub/nsub1)*S1
//   lstm: nsub1=2,S1=1024,S2=32, 8 subs -> BF[ct2][g*2+nt]; fc1: nsub1=8,S2=128; fc2: nsub1=4
// Block tile 32m x 128n-per-matrix-slice: grid 256 = 32 ct2 x 8 mg (ct2%8 == b%8 -> XCD-stable weights)
// Coherent (cross-block, cross-phase) data: h0,h1,U,xdec-est-cols -> ldfrag_dev/stq_dev ONLY.
// Smem (40KB): red[4][8][64] f32x4 = 32KB at 0; stage 8KB at 32768.

// amode: 0=cached, 1=mixed (kb>=6 coherent), 2=coherent
__device__ __forceinline__ void gemm_side(
    const u16* __restrict__ AF, int KBT, int amode,
    const u16* __restrict__ BF, int grp, int mg, int w, int lane,
    f32x4 acc[2][8])
{
    const int NI = KBT >> 2;                 // kbs owned by this wave (stride-4)
    for (int i0 = 0; i0 < NI; i0 += 4) {
        const int ni = (NI - i0) < 4 ? (NI - i0) : 4;
        f16x8 a0[4], a1[4];
        for (int i = 0; i < ni; ++i) {       // batch-issue coherent loads
            const int kb = w + 4 * (i0 + i);
            const u16* p0 = AF + (((size_t)(mg * 2 + 0) * KBT + kb) * 64 + lane) * 8;
            const u16* p1 = AF + (((size_t)(mg * 2 + 1) * KBT + kb) * 64 + lane) * 8;
            const bool coh = (amode == 2) || (amode == 1 && kb >= 6);
            a0[i] = coh ? ldfrag_dev(p0) : ldfrag(p0);
            a1[i] = coh ? ldfrag_dev(p1) : ldfrag(p1);
        }
        for (int i = 0; i < ni; ++i) {
            const int kb = w + 4 * (i0 + i);
            #pragma unroll
            for (int s = 0; s < 8; ++s) {
                f16x8 bf = ldfrag(BF + ((size_t)(grp * 8 + s) * KBT + kb) * 512 + lane * 8);
                acc[0][s] = __builtin_amdgcn_mfma_f32_16x16x32_f16(a0[i], bf, acc[0][s], 0, 0, 0);
                acc[1][s] = __builtin_amdgcn_mfma_f32_16x16x32_f16(a1[i], bf, acc[1][s], 0, 0, 0);
            }
        }
    }
}

// ---------- LSTM cell unit: block tile 32 rows x 32 cols-per-gate ----------
__device__ __forceinline__ void lstm_unit(
    const u16* __restrict__ AFa, int KBa, int amode,
    const u16* __restrict__ BFa,
    const u16* __restrict__ AFh,
    const u16* __restrict__ BFh,
    const float* __restrict__ bsum,
    float* __restrict__ cst,
    u16* __restrict__ h_out,
    int ct2, int mg, int tid, char* smem)
{
    f32x4 (*red)[8][64] = (f32x4 (*)[8][64])smem;
    u16* stage = (u16*)(smem + 32768);
    const int w    = tid >> 6;
    const int lane = tid & 63;
    const int l15  = lane & 15;
    const int quad = lane >> 4;

    f32x4 acc[2][8];
    #pragma unroll
    for (int t = 0; t < 2; ++t)
        #pragma unroll
        for (int s = 0; s < 8; ++s) acc[t][s] = (f32x4){0, 0, 0, 0};

    gemm_side(AFa, KBa, amode, BFa, ct2, mg, w, lane, acc);
    gemm_side(AFh, 32,  2,     BFh, ct2, mg, w, lane, acc);

    // cross-wave K-reduction: pass tt -> owner waves with (w>>1)==tt get tile (mt=mg*2+tt, nt=w&1)
    f32x4 z[4];
    #pragma unroll
    for (int tt = 0; tt < 2; ++tt) {
        #pragma unroll
        for (int s = 0; s < 8; ++s) red[w][s][lane] = acc[tt][s];
        __syncthreads();
        if ((w >> 1) == tt) {
            #pragma unroll
            for (int g = 0; g < 4; ++g) {
                const int s = g * 2 + (w & 1);
                z[g] = red[0][s][lane] + red[1][s][lane] + red[2][s][lane] + red[3][s][lane];
            }
        }
        __syncthreads();
    }

    const int nt = w & 1, tt = w >> 1;
    const int mt = mg * 2 + tt;
    const int col = ct2 * 32 + nt * 16 + l15;
    float bv[4];
    #pragma unroll
    for (int g = 0; g < 4; ++g) bv[g] = bsum[g * 1024 + col];
    #pragma unroll
    for (int r = 0; r < 4; ++r) {
        const int rl  = quad * 4 + r;
        const int row = mt * 16 + rl;
        const size_t gi = (size_t)row * 1024 + col;
        const float zi = z[0][r] + bv[0];
        const float zf = z[1][r] + bv[1];
        const float zg = z[2][r] + bv[2];
        const float zo = z[3][r] + bv[3];
        const float cv = cst[gi];            // block-private: cached
        const float cn = sigmoidf_(zf) * cv + sigmoidf_(zi) * tanhf(zg);
        cst[gi] = cn;
        stage[(tt * 16 + rl) * 32 + nt * 16 + l15] = f2h(sigmoidf_(zo) * tanhf(cn));
    }
    __syncthreads();
    // repack 32x32 tile -> A-frag (kb = ct2), 256 x 8B coherent stores
    {
        const int half = tid & 1;
        const int l    = (tid >> 1) & 63;
        const int mtl  = tid >> 7;           // 0,1
        u64 v = *(const u64*)&stage[(mtl * 16 + (l & 15)) * 32 + (l >> 4) * 8 + half * 4];
        stq_dev(h_out + (((size_t)(mg * 2 + mtl) * 32 + ct2) * 64 + l) * 8 + half * 4, v);
    }
    __syncthreads();
}

// ---------- fc1 unit: 64 blocks (8 ctq x 8 mgf), tile 32 rows x 128 cols ----------
__device__ __forceinline__ void fc1_unit(
    const u16* __restrict__ AFx, const u16* __restrict__ BFw,
    const float* __restrict__ bias, u16* __restrict__ U,
    int ctq, int mgf, int tid, char* smem)
{
    f32x4 (*red)[8][64] = (f32x4 (*)[8][64])smem;
    u16* stage = (u16*)(smem + 32768);
    const int w    = tid >> 6;
    const int lane = tid & 63;
    const int l15  = lane & 15;
    const int quad = lane >> 4;

    f32x4 acc[2][8];
    #pragma unroll
    for (int t = 0; t < 2; ++t)
        #pragma unroll
        for (int s = 0; s < 8; ++s) acc[t][s] = (f32x4){0, 0, 0, 0};

    gemm_side(AFx, 32, 2, BFw, ctq, mgf, w, lane, acc);

    f32x4 z[4];
    #pragma unroll
    for (int tt = 0; tt < 2; ++tt) {
        #pragma unroll
        for (int s = 0; s < 8; ++s) red[w][s][lane] = acc[tt][s];
        __syncthreads();
        if ((w >> 1) == tt) {
            #pragma unroll
            for (int q = 0; q < 4; ++q) {
                const int s = (w & 1) * 4 + q;
                z[q] = red[0][s][lane] + red[1][s][lane] + red[2][s][lane] + red[3][s][lane];
            }
        }
        __syncthreads();
    }

    const int tt = w >> 1;
    #pragma unroll
    for (int q = 0; q < 4; ++q) {
        const int cl = ((w & 1) * 4 + q) * 16 + l15;       // local col in [0,128)
        const float bv = bias[ctq * 128 + cl];
        #pragma unroll
        for (int r = 0; r < 4; ++r)
            stage[(tt * 16 + quad * 4 + r) * 128 + cl] = f2h(tanhf(z[q][r] + bv));
    }
    __syncthreads();
    // repack 32x128 -> A-frag kbs [ctq*4, +4): 1024 x 8B coherent stores, 4/thread
    #pragma unroll
    for (int s = 0; s < 4; ++s) {
        const int i    = s * 256 + tid;
        const int half = i & 1;
        const int l    = (i >> 1) & 63;
        const int kbl  = (i >> 7) & 3;
        const int mtl  = i >> 9;
        u64 v = *(const u64*)&stage[(mtl * 16 + (l & 15)) * 128 + kbl * 32 + (l >> 4) * 8 + half * 4];
        stq_dev(U + (((size_t)(mgf * 2 + mtl) * 32 + ctq * 4 + kbl) * 64 + l) * 8 + half * 4, v);
    }
    __syncthreads();
}

// ---------- fc2 unit: est = U @ fc_w2^T + b2 + est_in (16 blocks) ----------
__device__ __forceinline__ void fc2_unit(
    const u16* __restrict__ AFu, const u16* __restrict__ BFw2,
    const float* __restrict__ b2,
    const float* __restrict__ est_in, float* __restrict__ est_out,
    float* __restrict__ out_t, u16* __restrict__ xdec_t,
    int mtile, int tid, char* smem)
{
    u16* stage = (u16*)(smem + 32768);
    const int w    = tid >> 6;
    const int lane = tid & 63;
    const int l15  = lane & 15;
    const int quad = lane >> 4;

    f32x4 accp[4] = {{0,0,0,0},{0,0,0,0},{0,0,0,0},{0,0,0,0}};
    const u16* ap = AFu + ((size_t)(mtile * 32) * 64 + lane) * 8;
    const u16* bp = BFw2 + ((size_t)(w * 32) * 64 + lane) * 8;
    for (int i0 = 0; i0 < 32; i0 += 8) {
        f16x8 a[8];
        #pragma unroll
        for (int i = 0; i < 8; ++i) a[i] = ldfrag_dev(ap + (i0 + i) * 512);
        #pragma unroll
        for (int i = 0; i < 8; ++i)
            accp[i & 3] = __builtin_amdgcn_mfma_f32_16x16x32_f16(
                a[i], ldfrag(bp + (i0 + i) * 512), accp[i & 3], 0, 0, 0);
    }
    f32x4 acc = accp[0] + accp[1] + accp[2] + accp[3];

    const int col = w * 16 + l15;
    const float bv = b2[col];
    #pragma unroll
    for (int r = 0; r < 4; ++r) {
        const int rl = quad * 4 + r;
        const int row = mtile * 16 + rl;
        const float v = acc[r] + bv + est_in[row * 64 + col];
        est_out[row * 64 + col] = v;
        out_t[row * 64 + col] = v;
        stage[rl * 64 + col] = f2h(v);
    }
    __syncthreads();
    {
        const int half = tid & 1;
        const int cg   = (tid >> 1) & 7;
        const int rr   = tid >> 4;
        const int col0 = 192 + cg * 8;
        const int xkb  = col0 >> 5, xq = (col0 >> 3) & 3;
        u64 v = *(const u64*)&stage[rr * 64 + cg * 8 + half * 4];
        stq_dev(xdec_t + (((size_t)mtile * 8 + xkb) * 64 + xq * 16 + rr) * 8 + half * 4, v);
    }
    __syncthreads();
}

// ---------- shared parameter block ----------
struct MegaP {
    const u16 *xyenc; u16 *xdec;
    const u16 *wih0, *whh0, *wih1, *whh1, *fcw1, *fcw2;
    const float *b0s, *b1s, *fcb1, *fcb2;
    float *c0, *c1, *est0, *est1, *out;
    u16 *h0a, *h0b, *h1a, *h1b, *U;
    unsigned *bars;
};

// ---------- persistent mega-kernel ----------
__global__ __launch_bounds__(256, 1) void mega_k(MegaP p) {
    __shared__ __align__(16) char smem[40960];
    const int b   = blockIdx.x;
    const int tid = threadIdx.x;
    const int ct2 = b & 31;       // ct2%8 == b%8 -> XCD-stable weight slices
    const int mg  = b >> 5;

    u16* h0buf[2] = { p.h0a, p.h0b };
    u16* h1buf[2] = { p.h1a, p.h1b };
    float* estb[2] = { p.est0, p.est1 };
    int ph = 0;

    // encode: 65 phases, L0(s) || L1(s-1)
    for (int s = 0; s <= 64; ++s) {
        if (s < 64)
            lstm_unit(p.xyenc + (size_t)s * 65536, 8, /*amode=*/0, p.wih0,
                      h0buf[s & 1], p.whh0, p.b0s, p.c0, h0buf[(s + 1) & 1],
                      ct2, mg, tid, smem);
        if (s >= 1) {
            const int t = s - 1;
            lstm_unit(h0buf[(t + 1) & 1], 32, /*amode=*/2, p.wih1,
                      h1buf[t & 1], p.whh1, p.b1s, p.c1, h1buf[(t + 1) & 1],
                      ct2, mg, tid, smem);
        }
        gbar(p.bars, ph++);
    }

    // decode: 48 steps x 4 phases
    int cur = 0;
    for (int t = 0; t < 48; ++t) {
        if (b < 64)
            fc1_unit(h1buf[cur], p.fcw1, p.fcb1, p.U, b & 7, b >> 3, tid, smem);
        gbar(p.bars, ph++);
        if (b < 16)
            fc2_unit(p.U, p.fcw2, p.fcb2, estb[t & 1], estb[(t + 1) & 1],
                     p.out + (size_t)t * 16384, p.xdec + (size_t)t * 65536, b, tid, smem);
        gbar(p.bars, ph++);
        lstm_unit(p.xdec + (size_t)t * 65536, 8, /*amode=*/1, p.wih0,
                  h0buf[cur], p.whh0, p.b0s, p.c0, h0buf[cur ^ 1],
                  ct2, mg, tid, smem);
        gbar(p.bars, ph++);
        lstm_unit(h0buf[cur ^ 1], 32, /*amode=*/2, p.wih1,
                  h1buf[cur], p.whh1, p.b1s, p.c1, h1buf[cur ^ 1],
                  ct2, mg, tid, smem);
        gbar(p.bars, ph++);
        cur ^= 1;
    }
}

// ---------- fallback kernels (multi-launch; kernel boundaries give coherence) ----------
__global__ __launch_bounds__(256, 2) void enc_phase_k(MegaP p, int ph) {
    __shared__ __align__(16) char smem[40960];
    const int b   = blockIdx.x;
    const int tid = threadIdx.x;
    u16* h0buf[2] = { p.h0a, p.h0b };
    u16* h1buf[2] = { p.h1a, p.h1b };
    if (b < 256) {
        if (ph < 64)
            lstm_unit(p.xyenc + (size_t)ph * 65536, 8, 0, p.wih0,
                      h0buf[ph & 1], p.whh0, p.b0s, p.c0, h0buf[(ph + 1) & 1],
                      b & 31, b >> 5, tid, smem);
    } else {
        if (ph >= 1) {
            const int t = ph - 1, bb = b - 256;
            lstm_unit(h0buf[(t + 1) & 1], 32, 2, p.wih1,
                      h1buf[t & 1], p.whh1, p.b1s, p.c1, h1buf[(t + 1) & 1],
                      bb & 31, bb >> 5, tid, smem);
        }
    }
}
__global__ __launch_bounds__(256, 2) void fc1_fb_k(MegaP p, int cur) {
    __shared__ __align__(16) char smem[40960];
    u16* h1buf[2] = { p.h1a, p.h1b };
    fc1_unit(h1buf[cur], p.fcw1, p.fcb1, p.U,
             blockIdx.x & 7, blockIdx.x >> 3, threadIdx.x, smem);
}
__global__ __launch_bounds__(256, 2) void fc2_fb_k(MegaP p, int t) {
    __shared__ __align__(16) char smem[40960];
    float* estb[2] = { p.est0, p.est1 };
    fc2_unit(p.U, p.fcw2, p.fcb2, estb[t & 1], estb[(t + 1) & 1],
             p.out + (size_t)t * 16384, p.xdec + (size_t)t * 65536,
             blockIdx.x, threadIdx.x, smem);
}
__global__ __launch_bounds__(256, 2) void l0_fb_k(MegaP p, int t, int cur) {
    __shared__ __align__(16) char smem[40960];
    u16* h0buf[2] = { p.h0a, p.h0b };
    lstm_unit(p.xdec + (size_t)t * 65536, 8, 1, p.wih0,
              h0buf[cur], p.whh0, p.b0s, p.c0, h0buf[cur ^ 1],
              blockIdx.x & 31, blockIdx.x >> 5, threadIdx.x, smem);
}
__global__ __launch_bounds__(256, 2) void l1_fb_k(MegaP p, int cur) {
    __shared__ __align__(16) char smem[40960];
    u16* h0buf[2] = { p.h0a, p.h0b };
    u16* h1buf[2] = { p.h1a, p.h1b };
    lstm_unit(h0buf[cur ^ 1], 32, 2, p.wih1,
              h1buf[cur], p.whh1, p.b1s, p.c1, h1buf[cur ^ 1],
              blockIdx.x & 31, blockIdx.x >> 5, threadIdx.x, smem);
}

// ---------- setup kernels ----------
// row = grp*S2 + (sub % nsub1)*16 + (sub / nsub1)*S1
__global__ void cvt_bfrag_k(const float* __restrict__ src, u16* __restrict__ dst,
                            int K, int kbshift, int nsub1, int S1, int S2,
                            int nsubtot, int total) {
    int i = blockIdx.x * 256 + threadIdx.x;
    if (i >= total) return;
    const int lane = i & 63;
    const int kb   = (i >> 6) & ((1 << kbshift) - 1);
    const int rest = i >> (6 + kbshift);
    const int sub  = rest % nsubtot;
    const int grp  = rest / nsubtot;
    const int row  = grp * S2 + (sub % nsub1) * 16 + (sub / nsub1) * S1 + (lane & 15);
    const int colK = kb * 32 + (lane >> 4) * 8;
    const float* s = src + (size_t)row * K + colK;
    u16* d = dst + (size_t)i * 8;
    #pragma unroll
    for (int j = 0; j < 8; ++j) d[j] = f2h(s[j]);
}
__global__ void bias_k(const float* __restrict__ a, const float* __restrict__ b,
                       float* __restrict__ d, int n) {
    int i = blockIdx.x * 256 + threadIdx.x;
    if (i < n) d[i] = a[i] + b[i];
}
__global__ void init_k(u16* h0, u16* h1, float* c0, float* c1) {
    int i = blockIdx.x * 256 + threadIdx.x;
    h0[i] = 0; h1[i] = 0; c0[i] = 0.0f; c1[i] = 0.0f;
}
__global__ void estinit_k(const float* __restrict__ pre_y, float* __restrict__ est_prev) {
    int i = blockIdx.x * 256 + threadIdx.x;
    est_prev[i] = pre_y[63 * 16384 + i];
}
__global__ void pack_enc_k(const float* __restrict__ pre_x, const float* __restrict__ pre_y,
                           u16* __restrict__ xy) {
    int i = blockIdx.x * 256 + threadIdx.x;
    const int lane  = i & 63;
    const int kb    = (i >> 6) & 7;
    const int mtile = (i >> 9) & 15;
    const int t     = i >> 13;
    const int row   = mtile * 16 + (lane & 15);
    const int cb    = kb * 32 + (lane >> 4) * 8;
    u16* d = xy + (size_t)i * 8;
    #pragma unroll
    for (int j = 0; j < 8; ++j) {
        const int col = cb + j;
        const float v = (col < 192) ? pre_x[((size_t)t * 256 + row) * 192 + col]
                                    : pre_y[((size_t)t * 256 + row) * 64 + (col - 192)];
        d[j] = f2h(v);
    }
}
__global__ void pack_dec_k(const float* __restrict__ fx, u16* __restrict__ xd,
                           int total_threads) {
    int i = blockIdx.x * 256 + threadIdx.x;
    if (i >= total_threads) return;
    const int lane  = i & 63;
    int rest = i >> 6;
    const int kb    = rest % 6;  rest /= 6;
    const int mtile = rest & 15;
    const int t     = rest >> 4;
    const int row   = mtile * 16 + (lane & 15);
    const int cb    = kb * 32 + (lane >> 4) * 8;
    u16* d = xd + ((((size_t)t * 16 + mtile) * 8 + kb) * 64 + lane) * 8;
    #pragma unroll
    for (int j = 0; j < 8; ++j)
        d[j] = f2h(fx[((size_t)t * 256 + row) * 192 + cb + j]);
}

extern "C" void kernel_launch(void* const* d_in, const int* in_sizes, int n_in,
                              void* d_out, int out_size, void* d_ws, size_t ws_size,
                              hipStream_t stream) {
    const float* pre_x  = (const float*)d_in[0];
    const float* pre_y  = (const float*)d_in[1];
    const float* fx     = (const float*)d_in[2];
    const float* w_ih_0 = (const float*)d_in[3];
    const float* w_hh_0 = (const float*)d_in[4];
    const float* b_ih_0 = (const float*)d_in[5];
    const float* b_hh_0 = (const float*)d_in[6];
    const float* w_ih_1 = (const float*)d_in[7];
    const float* w_hh_1 = (const float*)d_in[8];
    const float* b_ih_1 = (const float*)d_in[9];
    const float* b_hh_1 = (const float*)d_in[10];
    const float* fc_w1  = (const float*)d_in[11];
    const float* fc_b1  = (const float*)d_in[12];
    const float* fc_w2  = (const float*)d_in[13];
    const float* fc_b2  = (const float*)d_in[14];

    size_t off = 0;
    char* wsb = (char*)d_ws;
    auto alloc = [&](size_t bytes) -> void* {
        void* p = wsb + off;
        off += (bytes + 255) & ~(size_t)255;
        return p;
    };
    u16* wih0 = (u16*)alloc((size_t)4096 * 256 * 2);
    u16* whh0 = (u16*)alloc((size_t)4096 * 1024 * 2);
    u16* wih1 = (u16*)alloc((size_t)4096 * 1024 * 2);
    u16* whh1 = (u16*)alloc((size_t)4096 * 1024 * 2);
    u16* fcw1 = (u16*)alloc((size_t)1024 * 1024 * 2);
    u16* fcw2 = (u16*)alloc((size_t)64 * 1024 * 2);
    float* b0s = (float*)alloc(4096 * 4);
    float* b1s = (float*)alloc(4096 * 4);
    u16* xyenc = (u16*)alloc((size_t)64 * 256 * 256 * 2);
    u16* xdec  = (u16*)alloc((size_t)48 * 256 * 256 * 2);
    u16* h0a = (u16*)alloc((size_t)256 * 1024 * 2);
    u16* h0b = (u16*)alloc((size_t)256 * 1024 * 2);
    u16* h1a = (u16*)alloc((size_t)256 * 1024 * 2);
    u16* h1b = (u16*)alloc((size_t)256 * 1024 * 2);
    float* c0 = (float*)alloc((size_t)256 * 1024 * 4);
    float* c1 = (float*)alloc((size_t)256 * 1024 * 4);
    u16* ufc  = (u16*)alloc((size_t)256 * 1024 * 2);
    float* est0 = (float*)alloc((size_t)256 * 64 * 4);
    float* est1 = (float*)alloc((size_t)256 * 64 * 4);
    unsigned* bars = (unsigned*)alloc(4096);

    hipMemsetAsync(bars, 0, 4096, stream);
    // lstm B: nsub1=2, S1=1024, S2=32, 8 subs, 32 grps
    cvt_bfrag_k<<<512, 256, 0, stream>>>(w_ih_0, wih0, 256, 3, 2, 1024, 32, 8, 32 * 8 * 8 * 64);
    cvt_bfrag_k<<<2048, 256, 0, stream>>>(w_hh_0, whh0, 1024, 5, 2, 1024, 32, 8, 32 * 8 * 32 * 64);
    cvt_bfrag_k<<<2048, 256, 0, stream>>>(w_ih_1, wih1, 1024, 5, 2, 1024, 32, 8, 32 * 8 * 32 * 64);
    cvt_bfrag_k<<<2048, 256, 0, stream>>>(w_hh_1, whh1, 1024, 5, 2, 1024, 32, 8, 32 * 8 * 32 * 64);
    // fc1 B: nsub1=8, S2=128, 8 subs, 8 grps
    cvt_bfrag_k<<<512, 256, 0, stream>>>(fc_w1, fcw1, 1024, 5, 8, 0, 128, 8, 8 * 8 * 32 * 64);
    // fc2 B: nsub1=4, 4 subs, 1 grp
    cvt_bfrag_k<<<32, 256, 0, stream>>>(fc_w2, fcw2, 1024, 5, 4, 0, 0, 4, 1 * 4 * 32 * 64);
    bias_k<<<16, 256, 0, stream>>>(b_ih_0, b_hh_0, b0s, 4096);
    bias_k<<<16, 256, 0, stream>>>(b_ih_1, b_hh_1, b1s, 4096);
    init_k<<<1024, 256, 0, stream>>>(h0a, h1a, c0, c1);
    estinit_k<<<64, 256, 0, stream>>>(pre_y, est0);
    pack_enc_k<<<2048, 256, 0, stream>>>(pre_x, pre_y, xyenc);
    pack_dec_k<<<1152, 256, 0, stream>>>(fx, xdec, 48 * 16 * 6 * 64);

    MegaP prm;
    prm.xyenc = xyenc;  prm.xdec = xdec;
    prm.wih0 = wih0;  prm.whh0 = whh0;  prm.wih1 = wih1;  prm.whh1 = whh1;
    prm.fcw1 = fcw1;  prm.fcw2 = fcw2;
    prm.b0s = b0s;  prm.b1s = b1s;  prm.fcb1 = fc_b1;  prm.fcb2 = fc_b2;
    prm.c0 = c0;  prm.c1 = c1;  prm.est0 = est0;  prm.est1 = est1;
    prm.out = (float*)d_out;
    prm.h0a = h0a;  prm.h0b = h0b;  prm.h1a = h1a;  prm.h1b = h1b;  prm.U = ufc;
    prm.bars = bars;

    void* kargs[] = { (void*)&prm };
    hipError_t ce = hipLaunchCooperativeKernel((const void*)mega_k, dim3(256), dim3(256),
                                               kargs, 0, stream);
    if (ce != hipSuccess) {
        for (int ph = 0; ph <= 64; ++ph)
            enc_phase_k<<<512, 256, 0, stream>>>(prm, ph);
        int cur = 0;
        for (int t = 0; t < 48; ++t) {
            fc1_fb_k<<<64, 256, 0, stream>>>(prm, cur);
            fc2_fb_k<<<16, 256, 0, stream>>>(prm, t);
            l0_fb_k<<<256, 256, 0, stream>>>(prm, t, cur);
            l1_fb_k<<<256, 256, 0, stream>>>(prm, cur);
            cur ^= 1;
        }
    }
}